// Round 1
// baseline (291863.330 us; speedup 1.0000x reference)
//
#include <hip/hip_runtime.h>
#include <math.h>

// Problem constants
#define Bz 512
#define Sz 128
#define Dz 128
#define Hz 1024
#define Lz 128
#define NSUB 4

#define GRID 256
#define BLOCK 512
#define NGRP 16   // independent groups (32 batch rows each)
#define GBLK 16   // blocks per group

typedef _Float16 half8 __attribute__((ext_vector_type(8)));
typedef float floatx4 __attribute__((ext_vector_type(4)));
typedef unsigned long long u64;

#define MFMA16(a, b, c) __builtin_amdgcn_mfma_f32_16x16x32_f16(a, b, c, 0, 0, 0)

// LDS frag-major layout (halfs), BK=128, one 48 KB buffer.
// unit = 16B lane-chunk; 3-bit XOR swizzle ((q<<1)|(c&1)) on unit low bits:
// every 8 consecutive staging lanes hit 8 distinct unit&7 -> all 32 banks
// per 128B write beat (old 1-bit swizzle covered only 2 bank-groups -> 4-way
// write conflict, measured 3.26e10 SQ_LDS_BANK_CONFLICT).
#define AHI_O 0
#define ALO_D 4096
#define BHI_O 8192
#define BLO_D 8192
#define CHUNK_HALFS 24576

enum { EPI_NONE = 0, EPI_Y = 1, EPI_H = 2 };

// dopri5 tableau row i+1 (input coeffs of stage i+1). Row 5 == 5th-order b
// weights (FSAL): h_next = y_6; stage-7 f-eval is dead and skipped.
__constant__ float DPA_C[6][6] = {
  {0.2f, 0.f, 0.f, 0.f, 0.f, 0.f},
  {0.075f, 0.225f, 0.f, 0.f, 0.f, 0.f},
  {44.f/45.f, -56.f/15.f, 32.f/9.f, 0.f, 0.f, 0.f},
  {19372.f/6561.f, -25360.f/2187.f, 64448.f/6561.f, -212.f/729.f, 0.f, 0.f},
  {9017.f/3168.f, -355.f/33.f, 46732.f/5247.f, 49.f/176.f, -5103.f/18656.f, 0.f},
  {35.f/384.f, 0.f, 500.f/1113.f, 125.f/192.f, -2187.f/6784.f, 11.f/84.f},
};

struct KArgs {
  const float *x, *t, *w_ih, *w_hh, *b_ih, *b_hh;
  const float *w0, *b0, *w1, *b1, *w2, *b2, *mu_w, *mu_b, *lv_w, *lv_b;
  float* out;
  float *h, *y, *t1, *t2, *gi, *gh;
  unsigned* bar;   // NGRP * 64 u32: slots[0..15], root at +32
};

// ---- IF$-level (cross-XCD coherent) accesses: relaxed agent atomics set
// sc0+sc1 (bypass L1+L2) with NO cache-wiping fences. Weights stay in L2.
__device__ __forceinline__ float2 ldc2(const float* p) {
  u64 v = __hip_atomic_load((u64*)p, __ATOMIC_RELAXED, __HIP_MEMORY_SCOPE_AGENT);
  union { u64 u; float2 f; } c; c.u = v; return c.f;
}
__device__ __forceinline__ float ldc1(const float* p) {
  unsigned v = __hip_atomic_load((unsigned*)p, __ATOMIC_RELAXED, __HIP_MEMORY_SCOPE_AGENT);
  union { unsigned u; float f; } c; c.u = v; return c.f;
}
__device__ __forceinline__ void stc1(float* p, float f) {
  union { float f; unsigned u; } c; c.f = f;
  // Ordering for the group barrier comes from the explicit vmcnt(0) drain in
  // gbar(); data stores themselves are relaxed agent-scope (sc0+sc1, no fence).
  __hip_atomic_store((unsigned*)p, c.u, __ATOMIC_RELAXED, __HIP_MEMORY_SCOPE_AGENT);
}

// Group barrier (16 blocks): equality-poll (poison-safe, no slot init needed).
// Data ordering: each wave drains its IF$ stores (vmcnt) before signaling;
// flags are relaxed agent atomics -> no L2 writeback/invalidate anywhere.
__device__ __forceinline__ void gbar(unsigned* gb, int jj, unsigned e) {
  asm volatile("s_waitcnt vmcnt(0) lgkmcnt(0)" ::: "memory");
  __syncthreads();
  const int t = threadIdx.x;
  if (jj == 0) {
    if (t >= 1 && t < GBLK) {
      while (__hip_atomic_load(&gb[t], __ATOMIC_RELAXED, __HIP_MEMORY_SCOPE_AGENT) != e)
        __builtin_amdgcn_s_sleep(1);
    }
    __syncthreads();
    if (t == 0)
      __hip_atomic_store(&gb[32], e, __ATOMIC_RELAXED, __HIP_MEMORY_SCOPE_AGENT);
  } else {
    if (t == 0) {
      __hip_atomic_store(&gb[jj], e, __ATOMIC_RELAXED, __HIP_MEMORY_SCOPE_AGENT);
      while (__hip_atomic_load(&gb[32], __ATOMIC_RELAXED, __HIP_MEMORY_SCOPE_AGENT) != e)
        __builtin_amdgcn_s_sleep(1);
    }
    __syncthreads();
  }
}

__device__ __forceinline__ void split8(float4 a, float4 b, half8& h, half8& l) {
  float v[8] = {a.x, a.y, a.z, a.w, b.x, b.y, b.z, b.w};
#pragma unroll
  for (int i = 0; i < 8; ++i) {
    _Float16 hh = (_Float16)v[i];
    h[i] = hh;
    l[i] = (_Float16)((v[i] - (float)hh) * 2048.0f);
  }
}

// One 32x64 tile of C[512,N] = A[512,K] @ W[N,K]^T + bias.
// A,W fp32; f16 hi/lo split at staging; 4 MFMA products -> ~2^-22 rel error.
// ACo: A rows are cross-block activations (IF$ loads). W always plain (L2).
// k0..k4 + h-tile live in caller registers across a substep (tile mapping is
// call-invariant), so dopri5 combines need no global k traffic.
template<bool ACo>
__device__ __forceinline__ void mfma_tile(
    const float* __restrict__ A, int lda, int K,
    const float* __restrict__ W, const float* __restrict__ bias,
    float* __restrict__ Cf, float* __restrict__ Yd, int ldc,
    int act, int epi, int stage, float hs,
    const float* __restrict__ hbuf,
    floatx4& K0, floatx4& K1, floatx4& K2, floatx4& K3, floatx4& K4,
    floatx4& Hc,
    int row0, int col0, _Float16* __restrict__ lds)
{
  const int tid = threadIdx.x;
  const int ln  = tid & 63;
  const int l16 = ln & 15;
  const int qd  = ln >> 4;
  const int wv  = tid >> 6;
  const int wr  = wv >> 2;     // 0..1 row-group
  const int wc  = wv & 3;      // 0..3 col-group

  // staging: thread owns 8-fp32 k-segments: 1 A row-seg + 2 W col-segs
  const int an   = tid >> 4;         // 0..31
  const int an15 = an & 15, ang = an >> 4;
  const int seg  = tid & 15;
  const int c_ = seg >> 2, q_ = seg & 3;
  // 3-bit bank swizzle: unit&7 distinct for all 8 (c_&1,q_) combos per octet
  const int ua = q_ * 16 + (an15 ^ ((q_ << 1) | (c_ & 1)));
  const int aoff  = AHI_O + (((c_ * 2 + ang) * 64 + ua) << 3);
  const int boff0 = BHI_O + (((c_ * 4 + ang) * 64 + ua) << 3);
  const int boff1 = BHI_O + (((c_ * 4 + 2 + ang) * 64 + ua) << 3);

  const float* gA  = A + (size_t)(row0 + an) * lda + (seg << 3);
  const float* gB0 = W + (size_t)(col0 + an) * K + (seg << 3);
  const float* gB1 = W + (size_t)(col0 + 32 + an) * K + (seg << 3);
  const int NC = K >> 7;

  floatx4 Phh = {0,0,0,0}, Phl = {0,0,0,0}, Plh = {0,0,0,0}, Pll = {0,0,0,0};

  float4 ra0, ra1, rb00, rb01, rb10, rb11;
  auto load6 = [&](int kk) {
    if (ACo) {
      float2 a0 = ldc2(gA + kk),     a1 = ldc2(gA + kk + 2);
      float2 a2 = ldc2(gA + kk + 4), a3 = ldc2(gA + kk + 6);
      ra0 = make_float4(a0.x, a0.y, a1.x, a1.y);
      ra1 = make_float4(a2.x, a2.y, a3.x, a3.y);
    } else {
      ra0 = *(const float4*)(gA + kk);
      ra1 = *(const float4*)(gA + kk + 4);
    }
    rb00 = *(const float4*)(gB0 + kk); rb01 = *(const float4*)(gB0 + kk + 4);
    rb10 = *(const float4*)(gB1 + kk); rb11 = *(const float4*)(gB1 + kk + 4);
  };
  auto store6 = [&]() {
    half8 h, l;
    split8(ra0, ra1, h, l);
    *(half8*)&lds[aoff] = h;  *(half8*)&lds[aoff + ALO_D] = l;
    split8(rb00, rb01, h, l);
    *(half8*)&lds[boff0] = h; *(half8*)&lds[boff0 + BLO_D] = l;
    split8(rb10, rb11, h, l);
    *(half8*)&lds[boff1] = h; *(half8*)&lds[boff1 + BLO_D] = l;
  };

  load6(0);
  __syncthreads();             // prior tile's readers done with buffer
  store6();
  if (NC > 1) load6(128);

  for (int c = 0; c < NC; ++c) {
    __syncthreads();           // chunk c visible
#pragma unroll
    for (int kq = 0; kq < 4; ++kq) {
      const int lnw = ln ^ ((qd << 1) | (kq & 1));     // same swizzle as writer
      const int ab = ((kq * 2 + wr) * 64 + lnw) << 3;
      const int bb = BHI_O + (((kq * 4 + wc) * 64 + lnw) << 3);
      half8 ah = *(const half8*)&lds[ab];
      half8 al = *(const half8*)&lds[ab + ALO_D];
      half8 bh = *(const half8*)&lds[bb];
      half8 bl = *(const half8*)&lds[bb + BLO_D];
      Phh = MFMA16(ah, bh, Phh);
      Phl = MFMA16(ah, bl, Phl);
      Plh = MFMA16(al, bh, Plh);
      Pll = MFMA16(al, bl, Pll);
    }
    __syncthreads();           // reads of chunk c done
    if (c + 1 < NC) {
      store6();
      if (c + 2 < NC) load6((c + 2) << 7);
    }
  }

  // Epilogue. C/D layout: col = lane&15, row = (lane>>4)*4 + i (m89-verified)
  const int col   = col0 + (wc << 4) + l16;
  const int rbase = row0 + (wr << 4) + (qd << 2);
  const float bb = bias[col];
#pragma unroll
  for (int i = 0; i < 4; ++i) {
    float v = Phh[i] + (Phl[i] + Plh[i]) * (1.0f/2048.0f)
            + Pll[i] * (1.0f/4194304.0f) + bb;
    if (act) v = tanhf(v);
    const size_t off = (size_t)(rbase + i) * ldc + col;
    if (epi == EPI_NONE) {
      stc1(&Cf[off], v);
    } else {
      if (stage == 0) Hc[i] = ldc1(&hbuf[off]);   // fresh h once per substep
      float yv = Hc[i];
      const float* DP = DPA_C[stage];
      if (stage > 0) yv = fmaf(hs * DP[0], K0[i], yv);
      if (stage > 1) { float c1 = DP[1]; if (c1 != 0.f) yv = fmaf(hs * c1, K1[i], yv); }
      if (stage > 2) yv = fmaf(hs * DP[2], K2[i], yv);
      if (stage > 3) yv = fmaf(hs * DP[3], K3[i], yv);
      if (stage > 4) yv = fmaf(hs * DP[4], K4[i], yv);
      yv = fmaf(hs * DP[stage], v, yv);
      if      (stage == 0) K0[i] = v;
      else if (stage == 1) K1[i] = v;
      else if (stage == 2) K2[i] = v;
      else if (stage == 3) K3[i] = v;
      else if (stage == 4) K4[i] = v;
      stc1(&Yd[off], yv);      // y_{stage+1}, or h in place (FSAL, stage 5)
    }
  }
}

template<bool ACo>
__device__ __forceinline__ void run_phase(
    const float* A, int lda, int K,
    const float* W, const float* bias, int N,
    float* Cf, float* Yd, int ldc, int act, int epi, int stage, float hs,
    const float* hbuf,
    floatx4& K0, floatx4& K1, floatx4& K2, floatx4& K3, floatx4& K4,
    floatx4& Hc, int g, int jj, _Float16* lds)
{
  const int tilesN = N >> 6;
  const int row0 = g << 5;     // group owns rows [g*32, g*32+32)
  if (tilesN >= GBLK) {
    const int tn0 = ((jj & 7) << 1) | (jj >> 3);
    for (int i = 0; i < (tilesN >> 4); ++i)
      mfma_tile<ACo>(A, lda, K, W, bias, Cf, Yd, ldc, act, epi, stage, hs,
                     hbuf, K0, K1, K2, K3, K4, Hc,
                     row0, (tn0 + (i << 4)) << 6, lds);
  } else {
    if (jj < tilesN)
      mfma_tile<ACo>(A, lda, K, W, bias, Cf, Yd, ldc, act, epi, stage, hs,
                     hbuf, K0, K1, K2, K3, K4, Hc, row0, jj << 6, lds);
  }
}

__global__ __launch_bounds__(BLOCK, 2) void ode_gru_kernel(KArgs a) {
  __shared__ __align__(16) _Float16 lds[CHUNK_HALFS];
  const int g  = blockIdx.x >> 4;
  const int jj = blockIdx.x & 15;
  unsigned* gb = a.bar + (g << 6);
  unsigned ep = 0;

  // zero this group's h rows via IF$ stores (ws poisoned every call)
  for (int i = jj * BLOCK + threadIdx.x; i < 32 * Hz; i += GBLK * BLOCK)
    stc1(a.h + (size_t)g * 32 * Hz + i, 0.f);
  gbar(gb, jj, ++ep);

  floatx4 K0 = {0,0,0,0}, K1 = {0,0,0,0}, K2 = {0,0,0,0};
  floatx4 K3 = {0,0,0,0}, K4 = {0,0,0,0}, Hc = {0,0,0,0};

  for (int s = 0; s < Sz; ++s) {
    if (s > 0) {
      const float dt = a.t[s] - a.t[s - 1];
      const float hs = dt * (1.0f / NSUB);
      for (int sub = 0; sub < NSUB; ++sub) {
        for (int st = 0; st < 6; ++st) {
          const float* yin = (st == 0) ? a.h : a.y;
          // L1 (tanh)
          run_phase<true>(yin, Hz, Hz, a.w0, a.b0, Hz, a.t1, nullptr, Hz,
                          1, EPI_NONE, 0, 0.f, nullptr,
                          K0, K1, K2, K3, K4, Hc, g, jj, lds);
          gbar(gb, jj, ++ep);
          // L2 (tanh)
          run_phase<true>(a.t1, Hz, Hz, a.w1, a.b1, Hz, a.t2, nullptr, Hz,
                          1, EPI_NONE, 0, 0.f, nullptr,
                          K0, K1, K2, K3, K4, Hc, g, jj, lds);
          gbar(gb, jj, ++ep);
          // L3 (linear) + fused dopri5 combine; k's stay in registers
          if (st < 5) {
            run_phase<true>(a.t2, Hz, Hz, a.w2, a.b2, Hz, nullptr, a.y, Hz,
                            0, EPI_Y, st, hs, a.h,
                            K0, K1, K2, K3, K4, Hc, g, jj, lds);
          } else {   // FSAL: h_next = y_6, written to h in place
            run_phase<true>(a.t2, Hz, Hz, a.w2, a.b2, Hz, nullptr, a.h, Hz,
                            0, EPI_H, 5, hs, a.h,
                            K0, K1, K2, K3, K4, Hc, g, jj, lds);
          }
          gbar(gb, jj, ++ep);
        }
      }
    }

    // GRU gates: gi = x_s@Wih^T+b ; gh = h@Whh^T+b (independent, one barrier)
    run_phase<false>(a.x + (size_t)s * Dz, Sz * Dz, Dz, a.w_ih, a.b_ih, 3 * Hz,
                     a.gi, nullptr, 3 * Hz, 0, EPI_NONE, 0, 0.f, nullptr,
                     K0, K1, K2, K3, K4, Hc, g, jj, lds);
    run_phase<true>(a.h, Hz, Hz, a.w_hh, a.b_hh, 3 * Hz,
                    a.gh, nullptr, 3 * Hz, 0, EPI_NONE, 0, 0.f, nullptr,
                    K0, K1, K2, K3, K4, Hc, g, jj, lds);
    gbar(gb, jj, ++ep);

    // GRU pointwise, h updated in place (group-local rows)
    for (int i = jj * BLOCK + threadIdx.x; i < 32 * Hz; i += GBLK * BLOCK) {
      const int r = g * 32 + (i >> 10);
      const int c = i & (Hz - 1);
      const size_t gx = (size_t)r * 3 * Hz + c;
      const size_t hx = (size_t)r * Hz + c;
      const float ir  = ldc1(a.gi + gx);
      const float iz  = ldc1(a.gi + gx + Hz);
      const float inn = ldc1(a.gi + gx + 2 * Hz);
      const float hr  = ldc1(a.gh + gx);
      const float hzv = ldc1(a.gh + gx + Hz);
      const float hnn = ldc1(a.gh + gx + 2 * Hz);
      const float hv  = ldc1(a.h + hx);
      const float rr  = 1.f / (1.f + expf(-(ir + hr)));
      const float zz  = 1.f / (1.f + expf(-(iz + hzv)));
      const float nnv = tanhf(inn + rr * hnn);
      stc1(a.h + hx, (1.f - zz) * nnv + zz * hv);
    }
    gbar(gb, jj, ++ep);
  }

  // Final projections (row-local; blocks jj<2 of each group do 1 tile each)
  run_phase<true>(a.h, Hz, Hz, a.mu_w, a.mu_b, Lz, a.out, nullptr, Lz,
                  0, EPI_NONE, 0, 0.f, nullptr,
                  K0, K1, K2, K3, K4, Hc, g, jj, lds);
  run_phase<true>(a.h, Hz, Hz, a.lv_w, a.lv_b, Lz, a.out + (size_t)Bz * Lz,
                  nullptr, Lz, 0, EPI_NONE, 0, 0.f, nullptr,
                  K0, K1, K2, K3, K4, Hc, g, jj, lds);
}

extern "C" void kernel_launch(void* const* d_in, const int* in_sizes, int n_in,
                              void* d_out, int out_size, void* d_ws, size_t ws_size,
                              hipStream_t stream) {
  KArgs a;
  a.x    = (const float*)d_in[0];
  a.t    = (const float*)d_in[1];
  a.w_ih = (const float*)d_in[2];
  a.w_hh = (const float*)d_in[3];
  a.b_ih = (const float*)d_in[4];
  a.b_hh = (const float*)d_in[5];
  a.w0   = (const float*)d_in[6];
  a.b0   = (const float*)d_in[7];
  a.w1   = (const float*)d_in[8];
  a.b1   = (const float*)d_in[9];
  a.w2   = (const float*)d_in[10];
  a.b2   = (const float*)d_in[11];
  a.mu_w = (const float*)d_in[12];
  a.mu_b = (const float*)d_in[13];
  a.lv_w = (const float*)d_in[14];
  a.lv_b = (const float*)d_in[15];
  a.out  = (float*)d_out;

  float* ws = (float*)d_ws;
  const size_t BH = (size_t)Bz * Hz;   // 524288 floats
  a.h  = ws + 0 * BH;
  a.y  = ws + 1 * BH;
  a.t1 = ws + 2 * BH;
  a.t2 = ws + 3 * BH;
  a.gi = ws + 4 * BH;            // [512, 3072] = 3*BH
  a.gh = ws + 7 * BH;            // [512, 3072] = 3*BH
  a.bar = (unsigned*)(ws + 10 * BH);   // 1024 u32; total ~20 MiB + 4 KiB
  (void)ws_size; (void)in_sizes; (void)n_in; (void)out_size;

  KArgs args_val = a;
  void* params[] = { &args_val };
  hipLaunchCooperativeKernel((void*)ode_gru_kernel, dim3(GRID), dim3(BLOCK),
                             params, 0, stream);
}

// Round 2
// 131094.141 us; speedup vs baseline: 2.2264x; 2.2264x over previous
//
#include <hip/hip_runtime.h>
#include <math.h>

// Problem constants
#define Bz 512
#define Sz 128
#define Dz 128
#define Hz 1024
#define Lz 128
#define NSUB 4

#define GRID 256
#define BLOCK 512
#define NGRP 16   // independent groups (32 batch rows each)
#define GBLK 16   // blocks per group

typedef _Float16 half8 __attribute__((ext_vector_type(8)));
typedef float floatx4 __attribute__((ext_vector_type(4)));
typedef unsigned long long u64;

#define MFMA16(a, b, c) __builtin_amdgcn_mfma_f32_16x16x32_f16(a, b, c, 0, 0, 0)

// LDS frag-major layout (halfs), BK=128, one 48 KB buffer.
// unit = 16B lane-chunk; 3-bit XOR swizzle ((q<<1)|(c&1)) on unit low bits:
// every 8 consecutive staging lanes hit 8 distinct unit&7 -> all 32 banks
// per 128B write beat (verified: SQ_LDS_BANK_CONFLICT 3.26e10 -> 0).
#define AHI_O 0
#define ALO_D 4096
#define BHI_O 8192
#define BLO_D 8192
#define CHUNK_HALFS 24576
// Allocation padded to 96 KB: floor(160KB/96KB)=1 makes it PHYSICALLY
// impossible for the CP to co-pack 2 blocks/CU (round-1 regression signature:
// occupancy 24.8%->11.9% at identical VGPR/LDS => half the CUs idle under the
// device-wide barrier). Only the first CHUNK_HALFS halfs are used.
#define LDS_HALFS 49152

enum { EPI_NONE = 0, EPI_Y = 1, EPI_H = 2 };

// dopri5 tableau row i+1 (input coeffs of stage i+1). Row 5 == 5th-order b
// weights (FSAL): h_next = y_6; stage-7 f-eval is dead and skipped.
__constant__ float DPA_C[6][6] = {
  {0.2f, 0.f, 0.f, 0.f, 0.f, 0.f},
  {0.075f, 0.225f, 0.f, 0.f, 0.f, 0.f},
  {44.f/45.f, -56.f/15.f, 32.f/9.f, 0.f, 0.f, 0.f},
  {19372.f/6561.f, -25360.f/2187.f, 64448.f/6561.f, -212.f/729.f, 0.f, 0.f},
  {9017.f/3168.f, -355.f/33.f, 46732.f/5247.f, 49.f/176.f, -5103.f/18656.f, 0.f},
  {35.f/384.f, 0.f, 500.f/1113.f, 125.f/192.f, -2187.f/6784.f, 11.f/84.f},
};

struct KArgs {
  const float *x, *t, *w_ih, *w_hh, *b_ih, *b_hh;
  const float *w0, *b0, *w1, *b1, *w2, *b2, *mu_w, *mu_b, *lv_w, *lv_b;
  float* out;
  float *h, *y, *t1, *t2, *gi, *gh;
  unsigned* bar;   // NGRP * 64 u32: slots[0..15], root at +32
};

// ---- IF$-level (cross-XCD coherent) accesses: relaxed agent atomics set
// sc0+sc1 (bypass L1+L2) with NO cache-wiping fences. Weights stay in L2.
__device__ __forceinline__ float2 ldc2(const float* p) {
  u64 v = __hip_atomic_load((u64*)p, __ATOMIC_RELAXED, __HIP_MEMORY_SCOPE_AGENT);
  union { u64 u; float2 f; } c; c.u = v; return c.f;
}
__device__ __forceinline__ float ldc1(const float* p) {
  unsigned v = __hip_atomic_load((unsigned*)p, __ATOMIC_RELAXED, __HIP_MEMORY_SCOPE_AGENT);
  union { unsigned u; float f; } c; c.u = v; return c.f;
}
__device__ __forceinline__ void stc1(float* p, float f) {
  union { float f; unsigned u; } c; c.f = f;
  // Ordering for the group barrier comes from the explicit vmcnt(0) drain in
  // gbar(); data stores themselves are relaxed agent-scope (sc0+sc1, no fence).
  __hip_atomic_store((unsigned*)p, c.u, __ATOMIC_RELAXED, __HIP_MEMORY_SCOPE_AGENT);
}

// Group barrier (16 blocks): equality-poll (poison-safe, no slot init needed).
// Data ordering: each wave drains its IF$ stores (vmcnt) before signaling;
// flags are relaxed agent atomics -> no L2 writeback/invalidate anywhere.
__device__ __forceinline__ void gbar(unsigned* gb, int jj, unsigned e) {
  asm volatile("s_waitcnt vmcnt(0) lgkmcnt(0)" ::: "memory");
  __syncthreads();
  const int t = threadIdx.x;
  if (jj == 0) {
    if (t >= 1 && t < GBLK) {
      while (__hip_atomic_load(&gb[t], __ATOMIC_RELAXED, __HIP_MEMORY_SCOPE_AGENT) != e)
        __builtin_amdgcn_s_sleep(1);
    }
    __syncthreads();
    if (t == 0)
      __hip_atomic_store(&gb[32], e, __ATOMIC_RELAXED, __HIP_MEMORY_SCOPE_AGENT);
  } else {
    if (t == 0) {
      __hip_atomic_store(&gb[jj], e, __ATOMIC_RELAXED, __HIP_MEMORY_SCOPE_AGENT);
      while (__hip_atomic_load(&gb[32], __ATOMIC_RELAXED, __HIP_MEMORY_SCOPE_AGENT) != e)
        __builtin_amdgcn_s_sleep(1);
    }
    __syncthreads();
  }
}

__device__ __forceinline__ void split8(float4 a, float4 b, half8& h, half8& l) {
  float v[8] = {a.x, a.y, a.z, a.w, b.x, b.y, b.z, b.w};
#pragma unroll
  for (int i = 0; i < 8; ++i) {
    _Float16 hh = (_Float16)v[i];
    h[i] = hh;
    l[i] = (_Float16)((v[i] - (float)hh) * 2048.0f);
  }
}

// One 32x64 tile of C[512,N] = A[512,K] @ W[N,K]^T + bias.
// A,W fp32; f16 hi/lo split at staging; 4 MFMA products -> ~2^-22 rel error.
// ACo: A rows are cross-block activations (IF$ loads). W always plain (L2).
// k0..k4 + h-tile live in caller registers across a substep (tile mapping is
// call-invariant), so dopri5 combines need no global k traffic.
template<bool ACo>
__device__ __forceinline__ void mfma_tile(
    const float* __restrict__ A, int lda, int K,
    const float* __restrict__ W, const float* __restrict__ bias,
    float* __restrict__ Cf, float* __restrict__ Yd, int ldc,
    int act, int epi, int stage, float hs,
    const float* __restrict__ hbuf,
    floatx4& K0, floatx4& K1, floatx4& K2, floatx4& K3, floatx4& K4,
    floatx4& Hc,
    int row0, int col0, _Float16* __restrict__ lds)
{
  const int tid = threadIdx.x;
  const int ln  = tid & 63;
  const int l16 = ln & 15;
  const int qd  = ln >> 4;
  const int wv  = tid >> 6;
  const int wr  = wv >> 2;     // 0..1 row-group
  const int wc  = wv & 3;      // 0..3 col-group

  // staging: thread owns 8-fp32 k-segments: 1 A row-seg + 2 W col-segs
  const int an   = tid >> 4;         // 0..31
  const int an15 = an & 15, ang = an >> 4;
  const int seg  = tid & 15;
  const int c_ = seg >> 2, q_ = seg & 3;
  // 3-bit bank swizzle: unit&7 distinct for all 8 (c_&1,q_) combos per octet
  const int ua = q_ * 16 + (an15 ^ ((q_ << 1) | (c_ & 1)));
  const int aoff  = AHI_O + (((c_ * 2 + ang) * 64 + ua) << 3);
  const int boff0 = BHI_O + (((c_ * 4 + ang) * 64 + ua) << 3);
  const int boff1 = BHI_O + (((c_ * 4 + 2 + ang) * 64 + ua) << 3);

  const float* gA  = A + (size_t)(row0 + an) * lda + (seg << 3);
  const float* gB0 = W + (size_t)(col0 + an) * K + (seg << 3);
  const float* gB1 = W + (size_t)(col0 + 32 + an) * K + (seg << 3);
  const int NC = K >> 7;

  floatx4 Phh = {0,0,0,0}, Phl = {0,0,0,0}, Plh = {0,0,0,0}, Pll = {0,0,0,0};

  float4 ra0, ra1, rb00, rb01, rb10, rb11;
  auto load6 = [&](int kk) {
    if (ACo) {
      float2 a0 = ldc2(gA + kk),     a1 = ldc2(gA + kk + 2);
      float2 a2 = ldc2(gA + kk + 4), a3 = ldc2(gA + kk + 6);
      ra0 = make_float4(a0.x, a0.y, a1.x, a1.y);
      ra1 = make_float4(a2.x, a2.y, a3.x, a3.y);
    } else {
      ra0 = *(const float4*)(gA + kk);
      ra1 = *(const float4*)(gA + kk + 4);
    }
    rb00 = *(const float4*)(gB0 + kk); rb01 = *(const float4*)(gB0 + kk + 4);
    rb10 = *(const float4*)(gB1 + kk); rb11 = *(const float4*)(gB1 + kk + 4);
  };
  auto store6 = [&]() {
    half8 h, l;
    split8(ra0, ra1, h, l);
    *(half8*)&lds[aoff] = h;  *(half8*)&lds[aoff + ALO_D] = l;
    split8(rb00, rb01, h, l);
    *(half8*)&lds[boff0] = h; *(half8*)&lds[boff0 + BLO_D] = l;
    split8(rb10, rb11, h, l);
    *(half8*)&lds[boff1] = h; *(half8*)&lds[boff1 + BLO_D] = l;
  };

  load6(0);
  __syncthreads();             // prior tile's readers done with buffer
  store6();
  if (NC > 1) load6(128);

  for (int c = 0; c < NC; ++c) {
    __syncthreads();           // chunk c visible
#pragma unroll
    for (int kq = 0; kq < 4; ++kq) {
      const int lnw = ln ^ ((qd << 1) | (kq & 1));     // same swizzle as writer
      const int ab = ((kq * 2 + wr) * 64 + lnw) << 3;
      const int bb = BHI_O + (((kq * 4 + wc) * 64 + lnw) << 3);
      half8 ah = *(const half8*)&lds[ab];
      half8 al = *(const half8*)&lds[ab + ALO_D];
      half8 bh = *(const half8*)&lds[bb];
      half8 bl = *(const half8*)&lds[bb + BLO_D];
      Phh = MFMA16(ah, bh, Phh);
      Phl = MFMA16(ah, bl, Phl);
      Plh = MFMA16(al, bh, Plh);
      Pll = MFMA16(al, bl, Pll);
    }
    __syncthreads();           // reads of chunk c done
    if (c + 1 < NC) {
      store6();
      if (c + 2 < NC) load6((c + 2) << 7);
    }
  }

  // Epilogue. C/D layout: col = lane&15, row = (lane>>4)*4 + i (m89-verified)
  const int col   = col0 + (wc << 4) + l16;
  const int rbase = row0 + (wr << 4) + (qd << 2);
  const float bb = bias[col];
#pragma unroll
  for (int i = 0; i < 4; ++i) {
    float v = Phh[i] + (Phl[i] + Plh[i]) * (1.0f/2048.0f)
            + Pll[i] * (1.0f/4194304.0f) + bb;
    if (act) v = tanhf(v);
    const size_t off = (size_t)(rbase + i) * ldc + col;
    if (epi == EPI_NONE) {
      stc1(&Cf[off], v);
    } else {
      if (stage == 0) Hc[i] = ldc1(&hbuf[off]);   // fresh h once per substep
      float yv = Hc[i];
      const float* DP = DPA_C[stage];
      if (stage > 0) yv = fmaf(hs * DP[0], K0[i], yv);
      if (stage > 1) { float c1 = DP[1]; if (c1 != 0.f) yv = fmaf(hs * c1, K1[i], yv); }
      if (stage > 2) yv = fmaf(hs * DP[2], K2[i], yv);
      if (stage > 3) yv = fmaf(hs * DP[3], K3[i], yv);
      if (stage > 4) yv = fmaf(hs * DP[4], K4[i], yv);
      yv = fmaf(hs * DP[stage], v, yv);
      if      (stage == 0) K0[i] = v;
      else if (stage == 1) K1[i] = v;
      else if (stage == 2) K2[i] = v;
      else if (stage == 3) K3[i] = v;
      else if (stage == 4) K4[i] = v;
      stc1(&Yd[off], yv);      // y_{stage+1}, or h in place (FSAL, stage 5)
    }
  }
}

template<bool ACo>
__device__ __forceinline__ void run_phase(
    const float* A, int lda, int K,
    const float* W, const float* bias, int N,
    float* Cf, float* Yd, int ldc, int act, int epi, int stage, float hs,
    const float* hbuf,
    floatx4& K0, floatx4& K1, floatx4& K2, floatx4& K3, floatx4& K4,
    floatx4& Hc, int g, int jj, _Float16* lds)
{
  const int tilesN = N >> 6;
  const int row0 = g << 5;     // group owns rows [g*32, g*32+32)
  if (tilesN >= GBLK) {
    const int tn0 = ((jj & 7) << 1) | (jj >> 3);
    for (int i = 0; i < (tilesN >> 4); ++i)
      mfma_tile<ACo>(A, lda, K, W, bias, Cf, Yd, ldc, act, epi, stage, hs,
                     hbuf, K0, K1, K2, K3, K4, Hc,
                     row0, (tn0 + (i << 4)) << 6, lds);
  } else {
    if (jj < tilesN)
      mfma_tile<ACo>(A, lda, K, W, bias, Cf, Yd, ldc, act, epi, stage, hs,
                     hbuf, K0, K1, K2, K3, K4, Hc, row0, jj << 6, lds);
  }
}

__global__ __launch_bounds__(BLOCK, 2) void ode_gru_kernel(KArgs a) {
  __shared__ __align__(16) _Float16 lds[LDS_HALFS];   // 96 KB: 1 block/CU guard
  const int g  = blockIdx.x >> 4;
  const int jj = blockIdx.x & 15;
  unsigned* gb = a.bar + (g << 6);
  unsigned ep = 0;

  // zero this group's h rows via IF$ stores (ws poisoned every call)
  for (int i = jj * BLOCK + threadIdx.x; i < 32 * Hz; i += GBLK * BLOCK)
    stc1(a.h + (size_t)g * 32 * Hz + i, 0.f);
  gbar(gb, jj, ++ep);

  floatx4 K0 = {0,0,0,0}, K1 = {0,0,0,0}, K2 = {0,0,0,0};
  floatx4 K3 = {0,0,0,0}, K4 = {0,0,0,0}, Hc = {0,0,0,0};

  for (int s = 0; s < Sz; ++s) {
    if (s > 0) {
      const float dt = a.t[s] - a.t[s - 1];
      const float hs = dt * (1.0f / NSUB);
      for (int sub = 0; sub < NSUB; ++sub) {
        for (int st = 0; st < 6; ++st) {
          const float* yin = (st == 0) ? a.h : a.y;
          // L1 (tanh)
          run_phase<true>(yin, Hz, Hz, a.w0, a.b0, Hz, a.t1, nullptr, Hz,
                          1, EPI_NONE, 0, 0.f, nullptr,
                          K0, K1, K2, K3, K4, Hc, g, jj, lds);
          gbar(gb, jj, ++ep);
          // L2 (tanh)
          run_phase<true>(a.t1, Hz, Hz, a.w1, a.b1, Hz, a.t2, nullptr, Hz,
                          1, EPI_NONE, 0, 0.f, nullptr,
                          K0, K1, K2, K3, K4, Hc, g, jj, lds);
          gbar(gb, jj, ++ep);
          // L3 (linear) + fused dopri5 combine; k's stay in registers
          if (st < 5) {
            run_phase<true>(a.t2, Hz, Hz, a.w2, a.b2, Hz, nullptr, a.y, Hz,
                            0, EPI_Y, st, hs, a.h,
                            K0, K1, K2, K3, K4, Hc, g, jj, lds);
          } else {   // FSAL: h_next = y_6, written to h in place
            run_phase<true>(a.t2, Hz, Hz, a.w2, a.b2, Hz, nullptr, a.h, Hz,
                            0, EPI_H, 5, hs, a.h,
                            K0, K1, K2, K3, K4, Hc, g, jj, lds);
          }
          gbar(gb, jj, ++ep);
        }
      }
    }

    // GRU gates: gi = x_s@Wih^T+b ; gh = h@Whh^T+b (independent, one barrier)
    run_phase<false>(a.x + (size_t)s * Dz, Sz * Dz, Dz, a.w_ih, a.b_ih, 3 * Hz,
                     a.gi, nullptr, 3 * Hz, 0, EPI_NONE, 0, 0.f, nullptr,
                     K0, K1, K2, K3, K4, Hc, g, jj, lds);
    run_phase<true>(a.h, Hz, Hz, a.w_hh, a.b_hh, 3 * Hz,
                    a.gh, nullptr, 3 * Hz, 0, EPI_NONE, 0, 0.f, nullptr,
                    K0, K1, K2, K3, K4, Hc, g, jj, lds);
    gbar(gb, jj, ++ep);

    // GRU pointwise, h updated in place (group-local rows)
    for (int i = jj * BLOCK + threadIdx.x; i < 32 * Hz; i += GBLK * BLOCK) {
      const int r = g * 32 + (i >> 10);
      const int c = i & (Hz - 1);
      const size_t gx = (size_t)r * 3 * Hz + c;
      const size_t hx = (size_t)r * Hz + c;
      const float ir  = ldc1(a.gi + gx);
      const float iz  = ldc1(a.gi + gx + Hz);
      const float inn = ldc1(a.gi + gx + 2 * Hz);
      const float hr  = ldc1(a.gh + gx);
      const float hzv = ldc1(a.gh + gx + Hz);
      const float hnn = ldc1(a.gh + gx + 2 * Hz);
      const float hv  = ldc1(a.h + hx);
      const float rr  = 1.f / (1.f + expf(-(ir + hr)));
      const float zz  = 1.f / (1.f + expf(-(iz + hzv)));
      const float nnv = tanhf(inn + rr * hnn);
      stc1(a.h + hx, (1.f - zz) * nnv + zz * hv);
    }
    gbar(gb, jj, ++ep);
  }

  // Final projections (row-local; blocks jj<2 of each group do 1 tile each)
  run_phase<true>(a.h, Hz, Hz, a.mu_w, a.mu_b, Lz, a.out, nullptr, Lz,
                  0, EPI_NONE, 0, 0.f, nullptr,
                  K0, K1, K2, K3, K4, Hc, g, jj, lds);
  run_phase<true>(a.h, Hz, Hz, a.lv_w, a.lv_b, Lz, a.out + (size_t)Bz * Lz,
                  nullptr, Lz, 0, EPI_NONE, 0, 0.f, nullptr,
                  K0, K1, K2, K3, K4, Hc, g, jj, lds);
}

extern "C" void kernel_launch(void* const* d_in, const int* in_sizes, int n_in,
                              void* d_out, int out_size, void* d_ws, size_t ws_size,
                              hipStream_t stream) {
  KArgs a;
  a.x    = (const float*)d_in[0];
  a.t    = (const float*)d_in[1];
  a.w_ih = (const float*)d_in[2];
  a.w_hh = (const float*)d_in[3];
  a.b_ih = (const float*)d_in[4];
  a.b_hh = (const float*)d_in[5];
  a.w0   = (const float*)d_in[6];
  a.b0   = (const float*)d_in[7];
  a.w1   = (const float*)d_in[8];
  a.b1   = (const float*)d_in[9];
  a.w2   = (const float*)d_in[10];
  a.b2   = (const float*)d_in[11];
  a.mu_w = (const float*)d_in[12];
  a.mu_b = (const float*)d_in[13];
  a.lv_w = (const float*)d_in[14];
  a.lv_b = (const float*)d_in[15];
  a.out  = (float*)d_out;

  float* ws = (float*)d_ws;
  const size_t BH = (size_t)Bz * Hz;   // 524288 floats
  a.h  = ws + 0 * BH;
  a.y  = ws + 1 * BH;
  a.t1 = ws + 2 * BH;
  a.t2 = ws + 3 * BH;
  a.gi = ws + 4 * BH;            // [512, 3072] = 3*BH
  a.gh = ws + 7 * BH;            // [512, 3072] = 3*BH
  a.bar = (unsigned*)(ws + 10 * BH);   // 1024 u32; total ~20 MiB + 4 KiB
  (void)ws_size; (void)in_sizes; (void)n_in; (void)out_size;

  KArgs args_val = a;
  void* params[] = { &args_val };
  hipLaunchCooperativeKernel((void*)ode_gru_kernel, dim3(GRID), dim3(BLOCK),
                             params, 0, stream);
}

// Round 3
// 130070.325 us; speedup vs baseline: 2.2439x; 1.0079x over previous
//
#include <hip/hip_runtime.h>
#include <math.h>

// Problem constants
#define Bz 512
#define Sz 128
#define Dz 128
#define Hz 1024
#define Lz 128
#define NSUB 4

#define GRID 256
#define BLOCK 512
#define NGRP 16   // independent groups (32 batch rows each)
#define GBLK 16   // blocks per group

typedef _Float16 half8 __attribute__((ext_vector_type(8)));
typedef float floatx4 __attribute__((ext_vector_type(4)));
typedef unsigned long long u64;

#define MFMA16(a, b, c) __builtin_amdgcn_mfma_f32_16x16x32_f16(a, b, c, 0, 0, 0)

// LDS frag-major layout (halfs), BK=128, DOUBLE-buffered 48 KB chunks.
// unit = 16B lane-chunk; 3-bit XOR swizzle ((q<<1)|(c&1)) on unit low bits:
// every 8 consecutive staging lanes hit 8 distinct unit&7 -> all 32 banks
// per 128B write beat (verified: SQ_LDS_BANK_CONFLICT 3.26e10 -> 0).
// Double-buffer: writes of chunk c+1 overlap reads of chunk c (other buffer),
// one __syncthreads per chunk (hipcc's lgkmcnt(0)-before-s_barrier drains all
// LDS ops, making each barrier a full fence). 96 KB total also keeps the
// 1-block/CU placement guard (round-1: 2 blocks/CU packing halved occupancy).
#define AHI_O 0
#define ALO_D 4096
#define BHI_O 8192
#define BLO_D 8192
#define CHUNK_HALFS 24576
#define LDS_HALFS 49152

enum { EPI_NONE = 0, EPI_Y = 1, EPI_H = 2 };

// dopri5 tableau row i+1 (input coeffs of stage i+1). Row 5 == 5th-order b
// weights (FSAL): h_next = y_6; stage-7 f-eval is dead and skipped.
__constant__ float DPA_C[6][6] = {
  {0.2f, 0.f, 0.f, 0.f, 0.f, 0.f},
  {0.075f, 0.225f, 0.f, 0.f, 0.f, 0.f},
  {44.f/45.f, -56.f/15.f, 32.f/9.f, 0.f, 0.f, 0.f},
  {19372.f/6561.f, -25360.f/2187.f, 64448.f/6561.f, -212.f/729.f, 0.f, 0.f},
  {9017.f/3168.f, -355.f/33.f, 46732.f/5247.f, 49.f/176.f, -5103.f/18656.f, 0.f},
  {35.f/384.f, 0.f, 500.f/1113.f, 125.f/192.f, -2187.f/6784.f, 11.f/84.f},
};

struct KArgs {
  const float *x, *t, *w_ih, *w_hh, *b_ih, *b_hh;
  const float *w0, *b0, *w1, *b1, *w2, *b2, *mu_w, *mu_b, *lv_w, *lv_b;
  float* out;
  float *h, *y, *t1, *t2, *gi, *gh;
  unsigned* bar;   // NGRP * 64 u32: slots[0..15], root at +32
};

// ---- IF$-level (cross-XCD coherent) accesses: relaxed agent atomics set
// sc0+sc1 (bypass L1+L2) with NO cache-wiping fences. Weights stay in L2.
__device__ __forceinline__ float2 ldc2(const float* p) {
  u64 v = __hip_atomic_load((u64*)p, __ATOMIC_RELAXED, __HIP_MEMORY_SCOPE_AGENT);
  union { u64 u; float2 f; } c; c.u = v; return c.f;
}
__device__ __forceinline__ float ldc1(const float* p) {
  unsigned v = __hip_atomic_load((unsigned*)p, __ATOMIC_RELAXED, __HIP_MEMORY_SCOPE_AGENT);
  union { unsigned u; float f; } c; c.u = v; return c.f;
}
__device__ __forceinline__ void stc1(float* p, float f) {
  union { float f; unsigned u; } c; c.f = f;
  // Ordering for the group barrier comes from the explicit vmcnt(0) drain in
  // gbar(); data stores themselves are relaxed agent-scope (sc0+sc1, no fence).
  __hip_atomic_store((unsigned*)p, c.u, __ATOMIC_RELAXED, __HIP_MEMORY_SCOPE_AGENT);
}

// Group barrier (16 blocks): equality-poll (poison-safe, no slot init needed).
// Data ordering: each wave drains its IF$ stores (vmcnt) before signaling;
// flags are relaxed agent atomics -> no L2 writeback/invalidate anywhere.
__device__ __forceinline__ void gbar(unsigned* gb, int jj, unsigned e) {
  asm volatile("s_waitcnt vmcnt(0) lgkmcnt(0)" ::: "memory");
  __syncthreads();
  const int t = threadIdx.x;
  if (jj == 0) {
    if (t >= 1 && t < GBLK) {
      while (__hip_atomic_load(&gb[t], __ATOMIC_RELAXED, __HIP_MEMORY_SCOPE_AGENT) != e)
        __builtin_amdgcn_s_sleep(1);
    }
    __syncthreads();
    if (t == 0)
      __hip_atomic_store(&gb[32], e, __ATOMIC_RELAXED, __HIP_MEMORY_SCOPE_AGENT);
  } else {
    if (t == 0) {
      __hip_atomic_store(&gb[jj], e, __ATOMIC_RELAXED, __HIP_MEMORY_SCOPE_AGENT);
      while (__hip_atomic_load(&gb[32], __ATOMIC_RELAXED, __HIP_MEMORY_SCOPE_AGENT) != e)
        __builtin_amdgcn_s_sleep(1);
    }
    __syncthreads();
  }
}

__device__ __forceinline__ void split8(float4 a, float4 b, half8& h, half8& l) {
  float v[8] = {a.x, a.y, a.z, a.w, b.x, b.y, b.z, b.w};
#pragma unroll
  for (int i = 0; i < 8; ++i) {
    _Float16 hh = (_Float16)v[i];
    h[i] = hh;
    l[i] = (_Float16)((v[i] - (float)hh) * 2048.0f);
  }
}

// One 32x64 tile of C[512,N] = A[512,K] @ W[N,K]^T + bias.
// A,W fp32; f16 hi/lo split at staging; 4 MFMA products -> ~2^-22 rel error.
// ACo: A rows are cross-block activations (IF$ loads). W always plain (L2).
// k0..k4 + h-tile live in caller registers across a substep (tile mapping is
// call-invariant), so dopri5 combines need no global k traffic.
template<bool ACo>
__device__ __forceinline__ void mfma_tile(
    const float* __restrict__ A, int lda, int K,
    const float* __restrict__ W, const float* __restrict__ bias,
    float* __restrict__ Cf, float* __restrict__ Yd, int ldc,
    int act, int epi, int stage, float hs,
    const float* __restrict__ hbuf,
    floatx4& K0, floatx4& K1, floatx4& K2, floatx4& K3, floatx4& K4,
    floatx4& Hc,
    int row0, int col0, _Float16* __restrict__ lds)
{
  const int tid = threadIdx.x;
  const int ln  = tid & 63;
  const int l16 = ln & 15;
  const int qd  = ln >> 4;
  const int wv  = tid >> 6;
  const int wr  = wv >> 2;     // 0..1 row-group
  const int wc  = wv & 3;      // 0..3 col-group

  // staging: thread owns 8-fp32 k-segments: 1 A row-seg + 2 W col-segs
  const int an   = tid >> 4;         // 0..31
  const int an15 = an & 15, ang = an >> 4;
  const int seg  = tid & 15;
  const int c_ = seg >> 2, q_ = seg & 3;
  // 3-bit bank swizzle: unit&7 distinct for all 8 (c_&1,q_) combos per octet
  const int ua = q_ * 16 + (an15 ^ ((q_ << 1) | (c_ & 1)));
  const int aoff  = AHI_O + (((c_ * 2 + ang) * 64 + ua) << 3);
  const int boff0 = BHI_O + (((c_ * 4 + ang) * 64 + ua) << 3);
  const int boff1 = BHI_O + (((c_ * 4 + 2 + ang) * 64 + ua) << 3);

  const float* gA  = A + (size_t)(row0 + an) * lda + (seg << 3);
  const float* gB0 = W + (size_t)(col0 + an) * K + (seg << 3);
  const float* gB1 = W + (size_t)(col0 + 32 + an) * K + (seg << 3);
  const int NC = K >> 7;

  floatx4 Phh = {0,0,0,0}, Phl = {0,0,0,0}, Plh = {0,0,0,0}, Pll = {0,0,0,0};

  float4 ra0, ra1, rb00, rb01, rb10, rb11;
  auto load6 = [&](int kk) {
    if (ACo) {
      float2 a0 = ldc2(gA + kk),     a1 = ldc2(gA + kk + 2);
      float2 a2 = ldc2(gA + kk + 4), a3 = ldc2(gA + kk + 6);
      ra0 = make_float4(a0.x, a0.y, a1.x, a1.y);
      ra1 = make_float4(a2.x, a2.y, a3.x, a3.y);
    } else {
      ra0 = *(const float4*)(gA + kk);
      ra1 = *(const float4*)(gA + kk + 4);
    }
    rb00 = *(const float4*)(gB0 + kk); rb01 = *(const float4*)(gB0 + kk + 4);
    rb10 = *(const float4*)(gB1 + kk); rb11 = *(const float4*)(gB1 + kk + 4);
  };
  auto store6 = [&](int bufo) {
    half8 h, l;
    split8(ra0, ra1, h, l);
    *(half8*)&lds[bufo + aoff] = h;  *(half8*)&lds[bufo + aoff + ALO_D] = l;
    split8(rb00, rb01, h, l);
    *(half8*)&lds[bufo + boff0] = h; *(half8*)&lds[bufo + boff0 + BLO_D] = l;
    split8(rb10, rb11, h, l);
    *(half8*)&lds[bufo + boff1] = h; *(half8*)&lds[bufo + boff1 + BLO_D] = l;
  };

  load6(0);
  __syncthreads();             // prior tile's readers done with both buffers
  store6(0);
  if (NC > 1) load6(128);

  for (int c = 0; c < NC; ++c) {
    __syncthreads();           // buf[c&1] writes drained+visible; c-1 readers done
    if (c + 1 < NC) {
      store6(((c + 1) & 1) ? CHUNK_HALFS : 0);   // other buffer: no hazard w/ reads
      if (c + 2 < NC) load6((c + 2) << 7);
    }
    const _Float16* __restrict__ lr = lds + ((c & 1) ? CHUNK_HALFS : 0);
#pragma unroll
    for (int kq = 0; kq < 4; ++kq) {
      const int lnw = ln ^ ((qd << 1) | (kq & 1));     // same swizzle as writer
      const int ab = ((kq * 2 + wr) * 64 + lnw) << 3;
      const int bb = BHI_O + (((kq * 4 + wc) * 64 + lnw) << 3);
      half8 ah = *(const half8*)&lr[ab];
      half8 al = *(const half8*)&lr[ab + ALO_D];
      half8 bh = *(const half8*)&lr[bb];
      half8 bl = *(const half8*)&lr[bb + BLO_D];
      Phh = MFMA16(ah, bh, Phh);
      Phl = MFMA16(ah, bl, Phl);
      Plh = MFMA16(al, bh, Plh);
      Pll = MFMA16(al, bl, Pll);
    }
    // no second barrier: next iteration's top barrier is the fence
  }

  // Epilogue. C/D layout: col = lane&15, row = (lane>>4)*4 + i (m89-verified)
  const int col   = col0 + (wc << 4) + l16;
  const int rbase = row0 + (wr << 4) + (qd << 2);
  const float bb = bias[col];
#pragma unroll
  for (int i = 0; i < 4; ++i) {
    float v = Phh[i] + (Phl[i] + Plh[i]) * (1.0f/2048.0f)
            + Pll[i] * (1.0f/4194304.0f) + bb;
    if (act) v = tanhf(v);
    const size_t off = (size_t)(rbase + i) * ldc + col;
    if (epi == EPI_NONE) {
      stc1(&Cf[off], v);
    } else {
      if (stage == 0) Hc[i] = ldc1(&hbuf[off]);   // fresh h once per substep
      float yv = Hc[i];
      const float* DP = DPA_C[stage];
      if (stage > 0) yv = fmaf(hs * DP[0], K0[i], yv);
      if (stage > 1) { float c1 = DP[1]; if (c1 != 0.f) yv = fmaf(hs * c1, K1[i], yv); }
      if (stage > 2) yv = fmaf(hs * DP[2], K2[i], yv);
      if (stage > 3) yv = fmaf(hs * DP[3], K3[i], yv);
      if (stage > 4) yv = fmaf(hs * DP[4], K4[i], yv);
      yv = fmaf(hs * DP[stage], v, yv);
      if      (stage == 0) K0[i] = v;
      else if (stage == 1) K1[i] = v;
      else if (stage == 2) K2[i] = v;
      else if (stage == 3) K3[i] = v;
      else if (stage == 4) K4[i] = v;
      stc1(&Yd[off], yv);      // y_{stage+1}, or h in place (FSAL, stage 5)
    }
  }
}

template<bool ACo>
__device__ __forceinline__ void run_phase(
    const float* A, int lda, int K,
    const float* W, const float* bias, int N,
    float* Cf, float* Yd, int ldc, int act, int epi, int stage, float hs,
    const float* hbuf,
    floatx4& K0, floatx4& K1, floatx4& K2, floatx4& K3, floatx4& K4,
    floatx4& Hc, int g, int jj, _Float16* lds)
{
  const int tilesN = N >> 6;
  const int row0 = g << 5;     // group owns rows [g*32, g*32+32)
  if (tilesN >= GBLK) {
    const int tn0 = ((jj & 7) << 1) | (jj >> 3);
    for (int i = 0; i < (tilesN >> 4); ++i)
      mfma_tile<ACo>(A, lda, K, W, bias, Cf, Yd, ldc, act, epi, stage, hs,
                     hbuf, K0, K1, K2, K3, K4, Hc,
                     row0, (tn0 + (i << 4)) << 6, lds);
  } else {
    if (jj < tilesN)
      mfma_tile<ACo>(A, lda, K, W, bias, Cf, Yd, ldc, act, epi, stage, hs,
                     hbuf, K0, K1, K2, K3, K4, Hc, row0, jj << 6, lds);
  }
}

__global__ __launch_bounds__(BLOCK, 2) void ode_gru_kernel(KArgs a) {
  __shared__ __align__(16) _Float16 lds[LDS_HALFS];   // 96 KB: dbuf + 1-block/CU guard
  const int g  = blockIdx.x >> 4;
  const int jj = blockIdx.x & 15;
  unsigned* gb = a.bar + (g << 6);
  unsigned ep = 0;

  // zero this group's h rows via IF$ stores (ws poisoned every call)
  for (int i = jj * BLOCK + threadIdx.x; i < 32 * Hz; i += GBLK * BLOCK)
    stc1(a.h + (size_t)g * 32 * Hz + i, 0.f);
  gbar(gb, jj, ++ep);

  floatx4 K0 = {0,0,0,0}, K1 = {0,0,0,0}, K2 = {0,0,0,0};
  floatx4 K3 = {0,0,0,0}, K4 = {0,0,0,0}, Hc = {0,0,0,0};

  for (int s = 0; s < Sz; ++s) {
    if (s > 0) {
      const float dt = a.t[s] - a.t[s - 1];
      const float hs = dt * (1.0f / NSUB);
      for (int sub = 0; sub < NSUB; ++sub) {
        for (int st = 0; st < 6; ++st) {
          const float* yin = (st == 0) ? a.h : a.y;
          // L1 (tanh)
          run_phase<true>(yin, Hz, Hz, a.w0, a.b0, Hz, a.t1, nullptr, Hz,
                          1, EPI_NONE, 0, 0.f, nullptr,
                          K0, K1, K2, K3, K4, Hc, g, jj, lds);
          gbar(gb, jj, ++ep);
          // L2 (tanh)
          run_phase<true>(a.t1, Hz, Hz, a.w1, a.b1, Hz, a.t2, nullptr, Hz,
                          1, EPI_NONE, 0, 0.f, nullptr,
                          K0, K1, K2, K3, K4, Hc, g, jj, lds);
          gbar(gb, jj, ++ep);
          // L3 (linear) + fused dopri5 combine; k's stay in registers
          if (st < 5) {
            run_phase<true>(a.t2, Hz, Hz, a.w2, a.b2, Hz, nullptr, a.y, Hz,
                            0, EPI_Y, st, hs, a.h,
                            K0, K1, K2, K3, K4, Hc, g, jj, lds);
          } else {   // FSAL: h_next = y_6, written to h in place
            run_phase<true>(a.t2, Hz, Hz, a.w2, a.b2, Hz, nullptr, a.h, Hz,
                            0, EPI_H, 5, hs, a.h,
                            K0, K1, K2, K3, K4, Hc, g, jj, lds);
          }
          gbar(gb, jj, ++ep);
        }
      }
    }

    // GRU gates: gi = x_s@Wih^T+b ; gh = h@Whh^T+b (independent, one barrier)
    run_phase<false>(a.x + (size_t)s * Dz, Sz * Dz, Dz, a.w_ih, a.b_ih, 3 * Hz,
                     a.gi, nullptr, 3 * Hz, 0, EPI_NONE, 0, 0.f, nullptr,
                     K0, K1, K2, K3, K4, Hc, g, jj, lds);
    run_phase<true>(a.h, Hz, Hz, a.w_hh, a.b_hh, 3 * Hz,
                    a.gh, nullptr, 3 * Hz, 0, EPI_NONE, 0, 0.f, nullptr,
                    K0, K1, K2, K3, K4, Hc, g, jj, lds);
    gbar(gb, jj, ++ep);

    // GRU pointwise, h updated in place (group-local rows)
    for (int i = jj * BLOCK + threadIdx.x; i < 32 * Hz; i += GBLK * BLOCK) {
      const int r = g * 32 + (i >> 10);
      const int c = i & (Hz - 1);
      const size_t gx = (size_t)r * 3 * Hz + c;
      const size_t hx = (size_t)r * Hz + c;
      const float ir  = ldc1(a.gi + gx);
      const float iz  = ldc1(a.gi + gx + Hz);
      const float inn = ldc1(a.gi + gx + 2 * Hz);
      const float hr  = ldc1(a.gh + gx);
      const float hzv = ldc1(a.gh + gx + Hz);
      const float hnn = ldc1(a.gh + gx + 2 * Hz);
      const float hv  = ldc1(a.h + hx);
      const float rr  = 1.f / (1.f + expf(-(ir + hr)));
      const float zz  = 1.f / (1.f + expf(-(iz + hzv)));
      const float nnv = tanhf(inn + rr * hnn);
      stc1(a.h + hx, (1.f - zz) * nnv + zz * hv);
    }
    gbar(gb, jj, ++ep);
  }

  // Final projections (row-local; blocks jj<2 of each group do 1 tile each)
  run_phase<true>(a.h, Hz, Hz, a.mu_w, a.mu_b, Lz, a.out, nullptr, Lz,
                  0, EPI_NONE, 0, 0.f, nullptr,
                  K0, K1, K2, K3, K4, Hc, g, jj, lds);
  run_phase<true>(a.h, Hz, Hz, a.lv_w, a.lv_b, Lz, a.out + (size_t)Bz * Lz,
                  nullptr, Lz, 0, EPI_NONE, 0, 0.f, nullptr,
                  K0, K1, K2, K3, K4, Hc, g, jj, lds);
}

extern "C" void kernel_launch(void* const* d_in, const int* in_sizes, int n_in,
                              void* d_out, int out_size, void* d_ws, size_t ws_size,
                              hipStream_t stream) {
  KArgs a;
  a.x    = (const float*)d_in[0];
  a.t    = (const float*)d_in[1];
  a.w_ih = (const float*)d_in[2];
  a.w_hh = (const float*)d_in[3];
  a.b_ih = (const float*)d_in[4];
  a.b_hh = (const float*)d_in[5];
  a.w0   = (const float*)d_in[6];
  a.b0   = (const float*)d_in[7];
  a.w1   = (const float*)d_in[8];
  a.b1   = (const float*)d_in[9];
  a.w2   = (const float*)d_in[10];
  a.b2   = (const float*)d_in[11];
  a.mu_w = (const float*)d_in[12];
  a.mu_b = (const float*)d_in[13];
  a.lv_w = (const float*)d_in[14];
  a.lv_b = (const float*)d_in[15];
  a.out  = (float*)d_out;

  float* ws = (float*)d_ws;
  const size_t BH = (size_t)Bz * Hz;   // 524288 floats
  a.h  = ws + 0 * BH;
  a.y  = ws + 1 * BH;
  a.t1 = ws + 2 * BH;
  a.t2 = ws + 3 * BH;
  a.gi = ws + 4 * BH;            // [512, 3072] = 3*BH
  a.gh = ws + 7 * BH;            // [512, 3072] = 3*BH
  a.bar = (unsigned*)(ws + 10 * BH);   // 1024 u32; total ~20 MiB + 4 KiB
  (void)ws_size; (void)in_sizes; (void)n_in; (void)out_size;

  KArgs args_val = a;
  void* params[] = { &args_val };
  hipLaunchCooperativeKernel((void*)ode_gru_kernel, dim3(GRID), dim3(BLOCK),
                             params, 0, stream);
}